// Round 17
// baseline (144.290 us; speedup 1.0000x reference)
//
#include <hip/hip_runtime.h>

#define NDIM 2048
#define FDIM 64
#define KDIM 8
#define BDIM 32
#define TN   16     // tile rows (n)
#define TM   256    // tile cols (m) -> 1 KB contiguous per output row segment
#define PROW  260   // f32 elems per epilogue-panel row (256 + 4)
#define PLANES 4    // b-planes per epilogue pass

typedef __attribute__((ext_vector_type(8))) short short8;
typedef __attribute__((ext_vector_type(4))) float f32x4;

static __device__ __forceinline__ unsigned short f2bf(float x) {
    unsigned u = __float_as_uint(x);                 // RNE to bf16
    return (unsigned short)((u + 0x7fffu + ((u >> 16) & 1u)) >> 16);
}

// Load 8 consecutive f32 from global (L2-resident L), convert to bf16 short8.
static __device__ __forceinline__ short8 ld_frag(const float* base) {
    const f32x4 x0 = *(const f32x4*)base;
    const f32x4 x1 = *(const f32x4*)(base + 4);
    short8 r;
    r[0] = (short)f2bf(x0[0]); r[1] = (short)f2bf(x0[1]);
    r[2] = (short)f2bf(x0[2]); r[3] = (short)f2bf(x0[3]);
    r[4] = (short)f2bf(x1[0]); r[5] = (short)f2bf(x1[1]);
    r[6] = (short)f2bf(x1[2]); r[7] = (short)f2bf(x1[3]);
    return r;
}

// ---------------------------------------------------------------------------
// R17 = R16 (best PASS, 119.6us) with the cov phase de-staged: MFMA fragments
// load DIRECTLY from global L (4MB, L2/L3-resident) with in-register f2bf.
// Deletes all 16 cov barriers + the cov LDS round-trip, so cov overlaps the
// co-resident block's store stream freely. Safe now: R14's discriminator
// proved the R6/R7/R9 failures were the f32x4 vector-mix of acc (R7 failed
// WITH staged cov), not global-direct fragment loads. Fragment addresses are
// algebraically identical to the staged path:
//   af[s]    <- Lk[(n0 + l15)*64            + s*32 + l4*8 .. +7]
//   bv[j][s] <- Lk[(m0 + w*64+j*16+l15)*64  + s*32 + l4*8 .. +7]
// Epilogue verbatim R16: scalar mix (vector-mix = proven miscompile), LDS
// scatter, 1KB-row readback, nontemporal stores, lgkmcnt-only barriers.
// One __syncthreads() before the epilogue covers the pl[] handoff.
// ---------------------------------------------------------------------------
__global__ __launch_bounds__(256, 2) void rfm_fused_mfma(
    const float* __restrict__ p, const float* __restrict__ L,
    const float* __restrict__ sr, float* __restrict__ out)
{
    __shared__ float pl[BDIM * KDIM];
    __shared__ __align__(16) float smem[PLANES * TN * PROW];   // 66560 B

    float* const Parr0 = smem;
    float* const Parr1 = Parr0 + TN * PROW;
    float* const Parr2 = Parr1 + TN * PROW;
    float* const Parr3 = Parr2 + TN * PROW;

    const int m0 = blockIdx.x * TM;
    const int n0 = blockIdx.y * TN;
    const int t  = threadIdx.x;
    const int lane = t & 63;
    const int w   = t >> 6;        // wave 0..3: cols w*64..w*64+63
    const int l15 = lane & 15;
    const int l4  = lane >> 4;     // 0..3

    pl[t] = p[t];                  // covered by the pre-epilogue __syncthreads

    f32x4 acc[KDIM][4];
    #pragma unroll
    for (int k = 0; k < KDIM; ++k)
        #pragma unroll
        for (int j = 0; j < 4; ++j) acc[k][j] = (f32x4){0.f, 0.f, 0.f, 0.f};

    // ---- 1) cov phase: global-direct fragments + MFMA; NO LDS, NO barriers.
    const float* const An_base = L + (size_t)(n0 + l15) * FDIM + l4 * 8;
    const float* const Am_base = L + (size_t)(m0 + w * 64 + l15) * FDIM + l4 * 8;
    #pragma unroll
    for (int k = 0; k < KDIM; ++k) {
        const size_t ko = (size_t)k * (NDIM * FDIM);
        short8 af[2], bv[4][2];
        #pragma unroll
        for (int s = 0; s < 2; ++s)
            af[s] = ld_frag(An_base + ko + s * 32);
        #pragma unroll
        for (int j = 0; j < 4; ++j)
            #pragma unroll
            for (int s = 0; s < 2; ++s)
                bv[j][s] = ld_frag(Am_base + ko + (size_t)(j * 16) * FDIM + s * 32);
        #pragma unroll
        for (int j = 0; j < 4; ++j)
            #pragma unroll
            for (int s = 0; s < 2; ++s)
                acc[k][j] = __builtin_amdgcn_mfma_f32_16x16x32_bf16(
                    af[s], bv[j][s], acc[k][j], 0, 0, 0);
    }

    // Diagonal: D row = n-local = l4*4+reg, col = m-local = w*64+j*16+l15.
    #pragma unroll
    for (int j = 0; j < 4; ++j)
        #pragma unroll
        for (int reg = 0; reg < 4; ++reg) {
            const int gn = n0 + l4 * 4 + reg;
            const int gm = m0 + w * 64 + j * 16 + l15;
            if (gn == gm) {
                #pragma unroll
                for (int k = 0; k < KDIM; ++k) {
                    const float q = sr[k * NDIM + gn];
                    acc[k][j][reg] += q * q;
                }
            }
        }

    __syncthreads();   // pl[] visible to all; panels free to use

    // ---- 2) epilogue: 4 planes/pass x 8 passes (verbatim R16, NT stores) ----
    const size_t NN = (size_t)NDIM * NDIM;
    float* const Parr[PLANES] = { Parr0, Parr1, Parr2, Parr3 };
    const int scr = l4 * 4;                 // scatter row base (+reg)
    const int scc = w * 64 + l15;           // scatter col base (+j*16)
    float* const obase = out + (size_t)n0 * NDIM + m0 + lane * 4;

    #pragma unroll 1
    for (int b = 0; b < BDIM; b += PLANES) {
        // mix (SCALAR FMAs, all acc indices static) + scatter
        #pragma unroll
        for (int u = 0; u < PLANES; ++u) {
            float pb[KDIM];
            #pragma unroll
            for (int k = 0; k < KDIM; ++k) pb[k] = pl[(b + u) * KDIM + k];
            float* const Pu = Parr[u];
            #pragma unroll
            for (int j = 0; j < 4; ++j)
                #pragma unroll
                for (int reg = 0; reg < 4; ++reg) {
                    float v = 0.0f;
                    #pragma unroll
                    for (int k = 0; k < KDIM; ++k) v += pb[k] * acc[k][j][reg];
                    Pu[(scr + reg) * PROW + scc + j * 16] = v;
                }
        }
        asm volatile("s_waitcnt lgkmcnt(0)" ::: "memory");  // my ds_writes done
        __builtin_amdgcn_s_barrier();                        // all writes done
        __builtin_amdgcn_sched_barrier(0);

        // readback + store: one inst = one full row = 1 KB contiguous, NT
        #pragma unroll
        for (int u = 0; u < PLANES; ++u) {
            const float* const Pu = Parr[u];
            const size_t boff = (size_t)(b + u) * NN;
            #pragma unroll
            for (int rr = 0; rr < 4; ++rr) {
                const int row = w + 4 * rr;
                const f32x4 wv = *(const f32x4*)&Pu[row * PROW + lane * 4];
                __builtin_nontemporal_store(wv,
                    (f32x4*)(obase + boff + (size_t)row * NDIM));
            }
        }
        asm volatile("s_waitcnt lgkmcnt(0)" ::: "memory");  // my ds_reads done
        __builtin_amdgcn_s_barrier();                        // safe to overwrite
        __builtin_amdgcn_sched_barrier(0);
    }
}

extern "C" void kernel_launch(void* const* d_in, const int* in_sizes, int n_in,
                              void* d_out, int out_size, void* d_ws, size_t ws_size,
                              hipStream_t stream)
{
    const float* p  = (const float*)d_in[0];   // (B,K) = (32,8)
    const float* L  = (const float*)d_in[1];   // (K,N,F) = (8,2048,64)
    const float* sr = (const float*)d_in[2];   // (K,N)   = (8,2048)
    float* out = (float*)d_out;                // (B,N,N) = (32,2048,2048)

    dim3 grid(NDIM / TM, NDIM / TN);           // 8 x 128 = 1024 blocks
    hipLaunchKernelGGL(rfm_fused_mfma, grid, dim3(256), 0, stream,
                       p, L, sr, out);
}

// Round 18
// 130.136 us; speedup vs baseline: 1.1088x; 1.1088x over previous
//
#include <hip/hip_runtime.h>

#define NDIM 2048
#define FDIM 64
#define KDIM 8
#define BDIM 32
#define TN   16     // tile rows (n)
#define TM   256    // tile cols (m); wave w owns cols w*64..w*64+63
#define BFROW 72    // bf16 elems per staging row (64 + 8 pad)
#define PROW  260   // f32 elems per epilogue-panel row (256 + 4)
#define PLANES 4    // b-planes per epilogue pass

typedef __attribute__((ext_vector_type(8))) short short8;
typedef __attribute__((ext_vector_type(4))) float f32x4;

static __device__ __forceinline__ unsigned short f2bf(float x) {
    unsigned u = __float_as_uint(x);                 // RNE to bf16
    return (unsigned short)((u + 0x7fffu + ((u >> 16) & 1u)) >> 16);
}

// ---------------------------------------------------------------------------
// R18 = R16 (best PASS, 119.6us) with a WAVE-PRIVATE, BARRIER-FREE epilogue.
// R16's 16 epilogue barriers existed only because readback rows crossed wave
// scatter regions. Now wave w reads back only its own 64-col slab (the exact
// elements it scattered), so ds_write -> lgkmcnt(0) -> ds_read is wave-local:
// ZERO barriers after the post-cov __syncthreads. Waves free-run, overlapping
// mix VALU with store issue. Store shape: 4 x 256-B segments per inst (R8 vs
// R13 proved >=256-B segments are rate-identical). Cov phase verbatim R16
// (staged LDS bf16 + MFMA; R17 proved de-staging loses 25us). Scalar mix only
// (f32x4 vector-mix of acc = proven miscompile R6/R7/R9). NT stores (R16: -5us).
// ---------------------------------------------------------------------------
__global__ __launch_bounds__(256, 2) void rfm_fused_mfma(
    const float* __restrict__ p, const float* __restrict__ L,
    const float* __restrict__ sr, float* __restrict__ out)
{
    __shared__ float pl[BDIM * KDIM];
    __shared__ __align__(16) char smem[PLANES * TN * PROW * 4];   // 66560 B

    unsigned short* const An = (unsigned short*)smem;       // [TN][BFROW] bf16
    unsigned short* const Am = An + TN * BFROW;             // [TM][BFROW] bf16
    float* const Parr0 = (float*)smem;                      // 4 panels [TN][PROW]
    float* const Parr1 = Parr0 + TN * PROW;
    float* const Parr2 = Parr1 + TN * PROW;
    float* const Parr3 = Parr2 + TN * PROW;

    const int m0 = blockIdx.x * TM;
    const int n0 = blockIdx.y * TN;
    const int t  = threadIdx.x;
    const int lane = t & 63;
    const int w   = t >> 6;        // wave 0..3: cols w*64..w*64+63
    const int l15 = lane & 15;
    const int l4  = lane >> 4;     // 0..3

    pl[t] = p[t];                  // covered by first __syncthreads below

    f32x4 acc[KDIM][4];
    #pragma unroll
    for (int k = 0; k < KDIM; ++k)
        #pragma unroll
        for (int j = 0; j < 4; ++j) acc[k][j] = (f32x4){0.f, 0.f, 0.f, 0.f};

    // ---- 1) cov phase: staged bf16 LDS + MFMA (verbatim R16) ----
    #pragma unroll
    for (int k = 0; k < KDIM; ++k) {
        const float* Lk = L + (size_t)k * (NDIM * FDIM);

        // An: 16 rows x 16 float4 = 256 float4 (1/thread)
        {
            const int row = t >> 4;
            const int fc  = (t & 15) << 2;
            const float4 va = *(const float4*)&Lk[(size_t)(n0 + row) * FDIM + fc];
            ushort4 ua;
            ua.x = f2bf(va.x); ua.y = f2bf(va.y); ua.z = f2bf(va.z); ua.w = f2bf(va.w);
            *(ushort4*)&An[row * BFROW + fc] = ua;
        }
        // Am: 256 rows x 16 float4 = 4096 float4 (16/thread)
        #pragma unroll
        for (int r = 0; r < 16; ++r) {
            const int idx = t + r * 256;
            const int row = idx >> 4;
            const int fc  = (idx & 15) << 2;
            const float4 vb = *(const float4*)&Lk[(size_t)(m0 + row) * FDIM + fc];
            ushort4 ub;
            ub.x = f2bf(vb.x); ub.y = f2bf(vb.y); ub.z = f2bf(vb.z); ub.w = f2bf(vb.w);
            *(ushort4*)&Am[row * BFROW + fc] = ub;
        }
        __syncthreads();

        short8 af[2], bv[4][2];
        #pragma unroll
        for (int s = 0; s < 2; ++s)
            af[s] = *(const short8*)&An[l15 * BFROW + s * 32 + l4 * 8];
        #pragma unroll
        for (int j = 0; j < 4; ++j)
            #pragma unroll
            for (int s = 0; s < 2; ++s)
                bv[j][s] = *(const short8*)
                    &Am[(w * 64 + j * 16 + l15) * BFROW + s * 32 + l4 * 8];
        #pragma unroll
        for (int j = 0; j < 4; ++j)
            #pragma unroll
            for (int s = 0; s < 2; ++s)
                acc[k][j] = __builtin_amdgcn_mfma_f32_16x16x32_bf16(
                    af[s], bv[j][s], acc[k][j], 0, 0, 0);
        __syncthreads();   // panels consumed; next k (or epilogue) may overwrite
    }

    // Diagonal: D row = n-local = l4*4+reg, col = m-local = w*64+j*16+l15.
    #pragma unroll
    for (int j = 0; j < 4; ++j)
        #pragma unroll
        for (int reg = 0; reg < 4; ++reg) {
            const int gn = n0 + l4 * 4 + reg;
            const int gm = m0 + w * 64 + j * 16 + l15;
            if (gn == gm) {
                #pragma unroll
                for (int k = 0; k < KDIM; ++k) {
                    const float q = sr[k * NDIM + gn];
                    acc[k][j][reg] += q * q;
                }
            }
        }

    // ---- 2) epilogue: wave-private slabs, ZERO barriers ----
    // Scatter (same formulas as R16): row = l4*4+reg, col = w*64 + j*16 + l15.
    // Readback: wave w reads ONLY cols w*64..w*64+63 -> wave-local ordering
    // via lgkmcnt(0); no s_barrier to kernel end.
    const size_t NN = (size_t)NDIM * NDIM;
    float* const Parr[PLANES] = { Parr0, Parr1, Parr2, Parr3 };
    const int scr = l4 * 4;                 // scatter row base (+reg)
    const int scc = w * 64 + l15;           // scatter col base (+j*16)
    const int rbc = w * 64 + l15 * 4;       // readback col (float4) in own slab
    float* const obase = out + (size_t)n0 * NDIM + m0 + rbc;

    #pragma unroll 1
    for (int b = 0; b < BDIM; b += PLANES) {
        // mix (SCALAR FMAs, all acc indices static) + scatter to own slab
        #pragma unroll
        for (int u = 0; u < PLANES; ++u) {
            float pb[KDIM];
            #pragma unroll
            for (int k = 0; k < KDIM; ++k) pb[k] = pl[(b + u) * KDIM + k];
            float* const Pu = Parr[u];
            #pragma unroll
            for (int j = 0; j < 4; ++j)
                #pragma unroll
                for (int reg = 0; reg < 4; ++reg) {
                    float v = 0.0f;
                    #pragma unroll
                    for (int k = 0; k < KDIM; ++k) v += pb[k] * acc[k][j][reg];
                    Pu[(scr + reg) * PROW + scc + j * 16] = v;
                }
        }
        asm volatile("s_waitcnt lgkmcnt(0)" ::: "memory");  // own ds_writes done
        __builtin_amdgcn_sched_barrier(0);

        // readback own slab + NT stores: 4 insts/plane, 4 x 256-B segs each
        #pragma unroll
        for (int u = 0; u < PLANES; ++u) {
            const float* const Pu = Parr[u];
            const size_t boff = (size_t)(b + u) * NN;
            #pragma unroll
            for (int rr = 0; rr < 4; ++rr) {
                const int row = l4 + 4 * rr;
                const f32x4 wv = *(const f32x4*)&Pu[row * PROW + rbc];
                __builtin_nontemporal_store(wv,
                    (f32x4*)(obase + boff + (size_t)row * NDIM));
            }
        }
        asm volatile("s_waitcnt lgkmcnt(0)" ::: "memory");  // own ds_reads done
        __builtin_amdgcn_sched_barrier(0);   // safe to overwrite own slab
    }
}

extern "C" void kernel_launch(void* const* d_in, const int* in_sizes, int n_in,
                              void* d_out, int out_size, void* d_ws, size_t ws_size,
                              hipStream_t stream)
{
    const float* p  = (const float*)d_in[0];   // (B,K) = (32,8)
    const float* L  = (const float*)d_in[1];   // (K,N,F) = (8,2048,64)
    const float* sr = (const float*)d_in[2];   // (K,N)   = (8,2048)
    float* out = (float*)d_out;                // (B,N,N) = (32,2048,2048)

    dim3 grid(NDIM / TM, NDIM / TN);           // 8 x 128 = 1024 blocks
    hipLaunchKernelGGL(rfm_fused_mfma, grid, dim3(256), 0, stream,
                       p, L, sr, out);
}